// Round 5
// baseline (281.283 us; speedup 1.0000x reference)
//
#include <hip/hip_runtime.h>
#include <hip/hip_bf16.h>
#include <stdint.h>
#include <math.h>

#define SEQ 4096
#define DIM 1024
#define NHEADS 16
#define DHEAD 64
#define INNER 1024

typedef __hip_bfloat16 bf16;
typedef __attribute__((ext_vector_type(8))) short short8;
typedef __attribute__((ext_vector_type(4))) float floatx4;

// async global->LDS, 16B per lane; lane i's 16B lands at dest + i*16.
__device__ __forceinline__ void gll16(const bf16* g, bf16* l) {
    __builtin_amdgcn_global_load_lds(
        (const __attribute__((address_space(1))) unsigned int*)g,
        (__attribute__((address_space(3))) unsigned int*)l,
        16, 0, 0);
}

__device__ __forceinline__ unsigned short f2bf_bits(float f) {
    bf16 h = __float2bfloat16(f);
    return *reinterpret_cast<unsigned short*>(&h);
}

__device__ __forceinline__ uint2 pack4bf(float a, float b, float c, float d) {
    __hip_bfloat162 lo = __float22bfloat162_rn(float2{a, b});
    __hip_bfloat162 hi = __float22bfloat162_rn(float2{c, d});
    uint2 r;
    r.x = *reinterpret_cast<unsigned*>(&lo);
    r.y = *reinterpret_cast<unsigned*>(&hi);
    return r;
}

// ---------------- convert x (fp32 -> bf16), 4 elems/thread ----------------
__global__ __launch_bounds__(256) void convert_x_kernel(const float* __restrict__ x,
                                                        bf16* __restrict__ xb) {
    int i = (blockIdx.x * 256 + threadIdx.x) * 4;
    float4 f = *reinterpret_cast<const float4*>(x + i);
    unsigned long long p = (unsigned long long)f2bf_bits(f.x)
                         | ((unsigned long long)f2bf_bits(f.y) << 16)
                         | ((unsigned long long)f2bf_bits(f.z) << 32)
                         | ((unsigned long long)f2bf_bits(f.w) << 48);
    *reinterpret_cast<unsigned long long*>(xb + i) = p;
}

// ------------- transpose + convert weights: W[k][n] -> Wt[n][k] bf16 -------------
__global__ __launch_bounds__(256) void transpose_w_kernel(
        const float* __restrict__ W0, const float* __restrict__ W1,
        const float* __restrict__ W2, const float* __restrict__ W3,
        bf16* __restrict__ T0, bf16* __restrict__ T1,
        bf16* __restrict__ T2, bf16* __restrict__ T3) {
    const float* W; bf16* T;
    switch (blockIdx.z) {
        case 0:  W = W0; T = T0; break;
        case 1:  W = W1; T = T1; break;
        case 2:  W = W2; T = T2; break;
        default: W = W3; T = T3; break;
    }
    __shared__ float tile[32][33];
    int k0 = blockIdx.x * 32, n0 = blockIdx.y * 32;
    int tx = threadIdx.x, ty = threadIdx.y;
    #pragma unroll
    for (int i = 0; i < 4; i++)
        tile[ty + 8 * i][tx] = W[(size_t)(k0 + ty + 8 * i) * 1024 + n0 + tx];
    __syncthreads();
    #pragma unroll
    for (int i = 0; i < 4; i++)
        T[(size_t)(n0 + ty + 8 * i) * 1024 + k0 + tx] = __float2bfloat16(tile[tx][ty + 8 * i]);
}

// ------------- transpose V: Vh[h][n][d] -> Vt[h][d][n] (bf16) -------------
__global__ __launch_bounds__(256) void transpose_v_kernel(const bf16* __restrict__ Vh,
                                                          bf16* __restrict__ Vt) {
    __shared__ bf16 tile[32][33];
    int h = blockIdx.z;
    int n0 = blockIdx.x * 32, d0 = blockIdx.y * 32;
    int tx = threadIdx.x, ty = threadIdx.y;
    const bf16* src = Vh + (size_t)h * SEQ * DHEAD;
    bf16* dst = Vt + (size_t)h * DHEAD * SEQ;
    #pragma unroll
    for (int i = 0; i < 4; i++)
        tile[ty + 8 * i][tx] = src[(size_t)(n0 + ty + 8 * i) * DHEAD + d0 + tx];
    __syncthreads();
    #pragma unroll
    for (int i = 0; i < 4; i++)
        dst[(size_t)(d0 + ty + 8 * i) * SEQ + n0 + tx] = tile[tx][ty + 8 * i];
}

// ---------------- 128x128 bf16 MFMA GEMM tile body (K=1024), m97-style ----------------
__device__ __forceinline__ void gemm128_body(const bf16* __restrict__ A,
                                             const bf16* __restrict__ Bt,
                                             int m0, int n0, floatx4 acc[4][4]) {
    __shared__ __align__(16) bf16 As[8192];
    __shared__ __align__(16) bf16 Bs[8192];
    const int tid = threadIdx.x;
    const int wave = tid >> 6;
    const int lane = tid & 63;
    const int l15 = lane & 15;
    const int quad = lane >> 4;

    #pragma unroll
    for (int i = 0; i < 4; i++)
        #pragma unroll
        for (int j = 0; j < 4; j++)
            acc[i][j] = (floatx4){0.f, 0.f, 0.f, 0.f};

    for (int k0 = 0; k0 < 1024; k0 += 64) {
        __syncthreads();
        #pragma unroll
        for (int j = 0; j < 4; j++) {
            int t = wave * 4 + j;
            int row = (t >> 1) * 16 + l15;
            int kb = (t & 1) * 32 + quad * 8;
            gll16(A + (size_t)(m0 + row) * 1024 + k0 + kb, &As[t * 512]);
            gll16(Bt + (size_t)(n0 + row) * 1024 + k0 + kb, &Bs[t * 512]);
        }
        __syncthreads();
        #pragma unroll
        for (int ks = 0; ks < 2; ks++) {
            short8 af[4], bfr[4];
            #pragma unroll
            for (int i = 0; i < 4; i++)
                af[i] = *reinterpret_cast<const short8*>(
                    &As[((((wave >> 1) * 4 + i) * 2 + ks) * 512) + lane * 8]);
            #pragma unroll
            for (int j = 0; j < 4; j++)
                bfr[j] = *reinterpret_cast<const short8*>(
                    &Bs[((((wave & 1) * 4 + j) * 2 + ks) * 512) + lane * 8]);
            #pragma unroll
            for (int i = 0; i < 4; i++)
                #pragma unroll
                for (int j = 0; j < 4; j++)
                    acc[i][j] = __builtin_amdgcn_mfma_f32_16x16x32_bf16(af[i], bfr[j], acc[i][j], 0, 0, 0);
        }
    }
}

// ---------------- QKV projection: z selects Wq/Wk/Wv; writes head-major bf16 ----------------
// Q is scaled by beta*log2e so attention can use exp2 directly.
__global__ __launch_bounds__(256) void qkv_gemm_kernel(
        const bf16* __restrict__ xb,
        const bf16* __restrict__ Wqt, const bf16* __restrict__ Wkt, const bf16* __restrict__ Wvt,
        bf16* __restrict__ Qh, bf16* __restrict__ Kh, bf16* __restrict__ Vh) {
    const bf16* Bt; bf16* O; float scale = 1.0f;
    if (blockIdx.z == 0)      { Bt = Wqt; O = Qh; scale = 0.125f * 1.4426950408889634f; }
    else if (blockIdx.z == 1) { Bt = Wkt; O = Kh; }
    else                      { Bt = Wvt; O = Vh; }
    int n0 = blockIdx.x * 128, m0 = blockIdx.y * 128;
    floatx4 acc[4][4];
    gemm128_body(xb, Bt, m0, n0, acc);

    const int tid = threadIdx.x, wave = tid >> 6, lane = tid & 63;
    const int l15 = lane & 15, quad = lane >> 4;
    const int wm = (wave >> 1) * 64, wn = (wave & 1) * 64;
    #pragma unroll
    for (int i = 0; i < 4; i++)
        #pragma unroll
        for (int j = 0; j < 4; j++) {
            int col = n0 + wn + j * 16 + l15;   // inner index
            int h = col >> 6, d = col & 63;
            #pragma unroll
            for (int r = 0; r < 4; r++) {
                int row = m0 + wm + i * 16 + quad * 4 + r;  // C/D: row = quad*4+reg
                O[((size_t)h * SEQ + row) * DHEAD + d] = __float2bfloat16(acc[i][j][r] * scale);
            }
        }
}

// ---------------- output projection: out = Oa @ Wo + bo (fp32 out) ----------------
__global__ __launch_bounds__(256) void out_gemm_kernel(
        const bf16* __restrict__ Oa, const bf16* __restrict__ Wot,
        const float* __restrict__ bo, float* __restrict__ out) {
    int n0 = blockIdx.x * 128, m0 = blockIdx.y * 128;
    floatx4 acc[4][4];
    gemm128_body(Oa, Wot, m0, n0, acc);

    const int tid = threadIdx.x, wave = tid >> 6, lane = tid & 63;
    const int l15 = lane & 15, quad = lane >> 4;
    const int wm = (wave >> 1) * 64, wn = (wave & 1) * 64;
    #pragma unroll
    for (int i = 0; i < 4; i++)
        #pragma unroll
        for (int j = 0; j < 4; j++) {
            int col = n0 + wn + j * 16 + l15;
            float b = bo[col];
            #pragma unroll
            for (int r = 0; r < 4; r++) {
                int row = m0 + wm + i * 16 + quad * 4 + r;
                out[(size_t)row * DIM + col] = acc[i][j][r] + b;
            }
        }
}

// ---------------- causal flash attention, transposed-S, 128 q-rows/block ----------------
// Sᵀ = K·Qᵀ; per-lane softmax denom; Q pre-scaled by beta*log2e => p = exp2(s).
// Each wave: 32 q-rows (2 B-frag groups) => each K/V fragment read feeds 2-4 MFMAs.
// Grid 512 = 2 blocks/CU, all co-resident; ids paired so (i, i+256) have qt sums 31
// (uniform per-CU causal work). head = id&15 pins 2 heads per XCD (L2-resident K/V).
__global__ __launch_bounds__(256, 2) void attention_kernel(
        const bf16* __restrict__ Qh, const bf16* __restrict__ Kh,
        const bf16* __restrict__ Vt, bf16* __restrict__ Oa) {
    __shared__ __align__(16) bf16 Ksh[8192];     // 16 KB: frag t = keygrp*2 + khalf
    __shared__ __align__(16) bf16 Vsh[8192];     // 16 KB: frag t = dgrp*4 + kseg
    __shared__ __align__(16) bf16 Ps[4][4096];   // 8 KB/wave: frag f = g*4 + key/32
    const int tid = threadIdx.x, wave = tid >> 6, lane = tid & 63;
    const int l15 = lane & 15, quad = lane >> 4;
    const int id = blockIdx.x;
    const int head = id & 15;
    const int rid = id >> 4;                     // 0..31
    const int qt = (id < 256) ? (31 - rid) : (rid - 16);  // pair-balanced
    const int qw = qt * 128 + wave * 32;         // wave's first q-row
    const size_t hoff = (size_t)head * SEQ * DHEAD;
    const bf16* Qb = Qh + hoff;
    const bf16* Kb = Kh + hoff;
    const bf16* Vb = Vt + hoff;                  // [d][seq]

    // Q as B-operand fragments, 2 groups of 16 q-rows
    short8 bq[2][2];
    #pragma unroll
    for (int g = 0; g < 2; g++)
        #pragma unroll
        for (int s = 0; s < 2; s++)
            bq[g][s] = *reinterpret_cast<const short8*>(
                Qb + (size_t)(qw + g * 16 + l15) * DHEAD + s * 32 + quad * 8);

    floatx4 acc_o[2][4];                         // Oᵀ per group: d = c*16+quad*4+r, q = l15
    #pragma unroll
    for (int g = 0; g < 2; g++)
        #pragma unroll
        for (int c = 0; c < 4; c++) acc_o[g][c] = (floatx4){0.f, 0.f, 0.f, 0.f};
    float l_part[2] = {0.f, 0.f};                // per-lane softmax denom partials

    const int ntiles = qt + 1;                   // BK=128: tiles 0..qt
    for (int kt = 0; kt < ntiles; kt++) {
        const int kbase = kt * 128;
        __syncthreads();                         // prev-tile readers done
        #pragma unroll
        for (int j = 0; j < 4; j++) {
            int t = wave * 4 + j;                // t = 0..15 across 4 waves
            gll16(Kb + (size_t)(kbase + (t >> 1) * 16 + l15) * DHEAD + (t & 1) * 32 + quad * 8,
                  &Ksh[t * 512]);
            gll16(Vb + (size_t)((t >> 2) * 16 + l15) * SEQ + kbase + (t & 3) * 32 + quad * 8,
                  &Vsh[t * 512]);
        }
        __syncthreads();                         // staged tiles visible

        // Sᵀ = K·Qᵀ: each K fragment pair feeds both q-groups (4 MFMA / 2 reads)
        floatx4 st[2][8];
        #pragma unroll
        for (int g = 0; g < 2; g++)
            #pragma unroll
            for (int c = 0; c < 8; c++) st[g][c] = (floatx4){0.f, 0.f, 0.f, 0.f};
        #pragma unroll
        for (int c = 0; c < 8; c++) {
            short8 ak0 = *reinterpret_cast<const short8*>(&Ksh[(c * 2 + 0) * 512 + lane * 8]);
            short8 ak1 = *reinterpret_cast<const short8*>(&Ksh[(c * 2 + 1) * 512 + lane * 8]);
            st[0][c] = __builtin_amdgcn_mfma_f32_16x16x32_bf16(ak0, bq[0][0], st[0][c], 0, 0, 0);
            st[0][c] = __builtin_amdgcn_mfma_f32_16x16x32_bf16(ak1, bq[0][1], st[0][c], 0, 0, 0);
            st[1][c] = __builtin_amdgcn_mfma_f32_16x16x32_bf16(ak0, bq[1][0], st[1][c], 0, 0, 0);
            st[1][c] = __builtin_amdgcn_mfma_f32_16x16x32_bf16(ak1, bq[1][1], st[1][c], 0, 0, 0);
        }
        // causal mask: key = kbase + c*16 + quad*4 + r, q = qw + g*16 + l15
        #pragma unroll
        for (int g = 0; g < 2; g++) {
            if (kbase + 127 > qw + g * 16) {
                int base0 = kbase + quad * 4 - (qw + g * 16) - l15;
                #pragma unroll
                for (int c = 0; c < 8; c++) {
                    int base = base0 + c * 16;
                    #pragma unroll
                    for (int r = 0; r < 4; r++)
                        if (base + r > 0) st[g][c][r] = -1e30f;
                }
            }
        }
        // p = exp2(s) (Q pre-scaled by log2e); per-lane denom; pack into Ps frags
        #pragma unroll
        for (int g = 0; g < 2; g++)
            #pragma unroll
            for (int c = 0; c < 8; c++) {
                float p0 = exp2f(st[g][c][0]);
                float p1 = exp2f(st[g][c][1]);
                float p2 = exp2f(st[g][c][2]);
                float p3 = exp2f(st[g][c][3]);
                l_part[g] += (p0 + p1) + (p2 + p3);
                int elem = (g * 4 + (c >> 1)) * 512
                         + (l15 + 16 * ((c & 1) * 2 + (quad >> 1))) * 8 + (quad & 1) * 4;
                *reinterpret_cast<uint2*>(&Ps[wave][elem]) = pack4bf(p0, p1, p2, p3);
            }
        // Oᵀ += Vᵀ·Pᵀ: each V fragment feeds both q-groups
        #pragma unroll
        for (int s = 0; s < 4; s++) {
            short8 bp0 = *reinterpret_cast<const short8*>(&Ps[wave][(s) * 512 + lane * 8]);
            short8 bp1 = *reinterpret_cast<const short8*>(&Ps[wave][(4 + s) * 512 + lane * 8]);
            #pragma unroll
            for (int c = 0; c < 4; c++) {
                short8 av = *reinterpret_cast<const short8*>(&Vsh[(c * 4 + s) * 512 + lane * 8]);
                acc_o[0][c] = __builtin_amdgcn_mfma_f32_16x16x32_bf16(av, bp0, acc_o[0][c], 0, 0, 0);
                acc_o[1][c] = __builtin_amdgcn_mfma_f32_16x16x32_bf16(av, bp1, acc_o[1][c], 0, 0, 0);
            }
        }
    }
    // finalize per group: denom = sum over the 4 quad-lanes holding this q-row
    #pragma unroll
    for (int g = 0; g < 2; g++) {
        float l = l_part[g];
        l += __shfl_xor(l, 16, 64);
        l += __shfl_xor(l, 32, 64);
        float rcp = 1.0f / l;
        const int q = qw + g * 16 + l15;
        #pragma unroll
        for (int c = 0; c < 4; c++) {
            uint2 v = pack4bf(acc_o[g][c][0] * rcp, acc_o[g][c][1] * rcp,
                              acc_o[g][c][2] * rcp, acc_o[g][c][3] * rcp);
            *reinterpret_cast<uint2*>(Oa + (size_t)q * INNER + head * DHEAD + c * 16 + quad * 4) = v;
        }
    }
}

extern "C" void kernel_launch(void* const* d_in, const int* in_sizes, int n_in,
                              void* d_out, int out_size, void* d_ws, size_t ws_size,
                              hipStream_t stream) {
    const float* x  = (const float*)d_in[0];
    const float* Wq = (const float*)d_in[1];
    const float* Wk = (const float*)d_in[2];
    const float* Wv = (const float*)d_in[3];
    const float* Wo = (const float*)d_in[4];
    const float* bo = (const float*)d_in[5];
    float* out = (float*)d_out;

    char* ws = (char*)d_ws;
    size_t off = 0;
    bf16* xb  = (bf16*)(ws + off); off += (size_t)SEQ * DIM * 2;
    bf16* Wqt = (bf16*)(ws + off); off += (size_t)DIM * INNER * 2;
    bf16* Wkt = (bf16*)(ws + off); off += (size_t)DIM * INNER * 2;
    bf16* Wvt = (bf16*)(ws + off); off += (size_t)DIM * INNER * 2;
    bf16* Wot = (bf16*)(ws + off); off += (size_t)INNER * DIM * 2;
    bf16* Qh  = (bf16*)(ws + off); off += (size_t)NHEADS * SEQ * DHEAD * 2;
    bf16* Kh  = (bf16*)(ws + off); off += (size_t)NHEADS * SEQ * DHEAD * 2;
    bf16* Vh  = (bf16*)(ws + off); off += (size_t)NHEADS * SEQ * DHEAD * 2;
    bf16* Vtr = (bf16*)(ws + off); off += (size_t)NHEADS * DHEAD * SEQ * 2;
    bf16* Oa  = (bf16*)(ws + off); off += (size_t)SEQ * INNER * 2;  // ~56 MB total

    convert_x_kernel<<<(SEQ * DIM) / 1024, 256, 0, stream>>>(x, xb);
    transpose_w_kernel<<<dim3(32, 32, 4), dim3(32, 8), 0, stream>>>(Wq, Wk, Wv, Wo,
                                                                    Wqt, Wkt, Wvt, Wot);
    qkv_gemm_kernel<<<dim3(8, 32, 3), 256, 0, stream>>>(xb, Wqt, Wkt, Wvt, Qh, Kh, Vh);
    transpose_v_kernel<<<dim3(SEQ / 32, DHEAD / 32, NHEADS), dim3(32, 8), 0, stream>>>(Vh, Vtr);
    attention_kernel<<<512, 256, 0, stream>>>(Qh, Kh, Vtr, Oa);
    out_gemm_kernel<<<dim3(8, 32), 256, 0, stream>>>(Oa, Wot, bo, out);
}